// Round 2
// baseline (202.138 us; speedup 1.0000x reference)
//
#include <hip/hip_runtime.h>

// IRNN 8-direction scan. x: [8,32,256,256] f32. Outputs (concat in order):
// 0 up, 1 right, 2 down, 3 left, 4 zuoxia, 5 youxia, 6 zuoshang(==zuoxia), 7 youshang.
//
// Single merged kernel, 2560 one-wave blocks:
//   [0,256)    forward-vertical  : down(out2) + zuoxia(out4,out6) + youxia(out5), 1 plane each
//   [256,512)  backward-vertical : up(out0) + youshang(out7), 1 plane each
//   [512,1536) horizontal right  : out1, 64 rows each (LDS chunked scan)
//   [1536,2560) horizontal left  : out3

namespace {
constexpr int HH = 256;
constexpr int WW = 256;
constexpr int PLANE = HH * WW;                       // 65536
constexpr size_t TEN = (size_t)PLANE * 256;          // elems per output tensor

__device__ __forceinline__ float relu_f(float a) { return fmaxf(a, 0.0f); }
} // namespace

__global__ __launch_bounds__(64) void irnn_all(
    const float* __restrict__ x, float* __restrict__ out,
    const float* __restrict__ wup_p, const float* __restrict__ wdn_p,
    const float* __restrict__ wlf_p, const float* __restrict__ wrt_p)
{
    __shared__ float xs[64][33];      // horizontal roles only (in-place scan)

    const int bid = blockIdx.x;
    const int t = threadIdx.x;

    if (bid < 256) {
        // ---- forward vertical: down + zuoxia(+dup) + youxia, one plane ----
        const int plane = bid;
        const float wd = *wdn_p;
        const float* xp = x + (size_t)plane * PLANE + t * 4;
        float* o2 = out + 2 * TEN + (size_t)plane * PLANE + t * 4;
        float* o4 = out + 4 * TEN + (size_t)plane * PLANE + t * 4;
        float* o5 = out + 5 * TEN + (size_t)plane * PLANE + t * 4;
        float* o6 = out + 6 * TEN + (size_t)plane * PLANE + t * 4;

        float4 c2 = *(const float4*)xp;       // h=0 pass-through for all
        float4 c4 = c2, c5 = c2;
        *(float4*)o2 = c2; *(float4*)o4 = c4; *(float4*)o6 = c4; *(float4*)o5 = c5;

        float4 v = *(const float4*)(xp + WW);  // prefetch row 1
        for (int h = 1; h < HH; ++h) {
            float4 vn;
            if (h + 1 < HH) vn = *(const float4*)(xp + (h + 1) * WW);
            // down
            c2.x = relu_f(c2.x * wd + v.x);
            c2.y = relu_f(c2.y * wd + v.y);
            c2.z = relu_f(c2.z * wd + v.z);
            c2.w = relu_f(c2.w * wd + v.w);
            *(float4*)(o2 + h * WW) = c2;
            // zuoxia (shift right: out[h][w] = relu(out[h-1][w-1]*wd + x[h][w]))
            {
                float pw = __shfl_up(c4.w, 1);
                float4 n;
                n.x = (t == 0) ? v.x : relu_f(pw * wd + v.x);
                n.y = relu_f(c4.x * wd + v.y);
                n.z = relu_f(c4.y * wd + v.z);
                n.w = relu_f(c4.z * wd + v.w);
                *(float4*)(o4 + h * WW) = n;
                *(float4*)(o6 + h * WW) = n;
                c4 = n;
            }
            // youxia (shift left: out[h][w] = relu(out[h-1][w+1]*wd + x[h][w]))
            {
                float nx = __shfl_down(c5.x, 1);
                float4 n;
                n.x = relu_f(c5.y * wd + v.x);
                n.y = relu_f(c5.z * wd + v.y);
                n.z = relu_f(c5.w * wd + v.z);
                n.w = (t == 63) ? v.w : relu_f(nx * wd + v.w);
                *(float4*)(o5 + h * WW) = n;
                c5 = n;
            }
            v = vn;
        }
    } else if (bid < 512) {
        // ---- backward vertical: up + youshang, one plane ----
        const int plane = bid & 255;
        const float wu = *wup_p;
        const float wd = *wdn_p;
        const float* xp = x + (size_t)plane * PLANE + t * 4;
        float* o0 = out + 0 * TEN + (size_t)plane * PLANE + t * 4;
        float* o7 = out + 7 * TEN + (size_t)plane * PLANE + t * 4;

        float4 c0 = *(const float4*)(xp + (HH - 1) * WW);  // h=255 pass-through
        float4 c7 = c0;
        *(float4*)(o0 + (HH - 1) * WW) = c0;
        *(float4*)(o7 + (HH - 1) * WW) = c7;

        float4 v = *(const float4*)(xp + (HH - 2) * WW);   // prefetch row 254
        for (int h = HH - 2; h >= 0; --h) {
            float4 vn;
            if (h > 0) vn = *(const float4*)(xp + (h - 1) * WW);
            // up
            c0.x = relu_f(c0.x * wu + v.x);
            c0.y = relu_f(c0.y * wu + v.y);
            c0.z = relu_f(c0.z * wu + v.z);
            c0.w = relu_f(c0.w * wu + v.w);
            *(float4*)(o0 + h * WW) = c0;
            // youshang (out[h][w] = relu(out[h+1][w-1]*wd + x[h][w]))
            {
                float pw = __shfl_up(c7.w, 1);
                float4 n;
                n.x = (t == 0) ? v.x : relu_f(pw * wd + v.x);
                n.y = relu_f(c7.x * wd + v.y);
                n.z = relu_f(c7.y * wd + v.z);
                n.w = relu_f(c7.z * wd + v.w);
                *(float4*)(o7 + h * WW) = n;
                c7 = n;
            }
            v = vn;
        }
    } else {
        // ---- horizontal: right (out1) / left (out3), 64 rows per block ----
        const int dir = (bid >= 1536) ? 1 : 0;
        const int rb = (bid - 512) & 1023;
        const size_t row0 = (size_t)rb * 64;
        const int lrow = t >> 3;          // 8 lanes per row for load/store
        const int lcol = (t & 7) * 4;

        const float w = dir ? *wlf_p : *wrt_p;
        float* op = out + (size_t)(dir ? 3 : 1) * TEN;

        float carry = 0.0f;
        for (int ci = 0; ci < 8; ++ci) {
            const int cw = dir ? (7 - ci) : ci;
            const int wbase = cw * 32;

            for (int p = 0; p < 8; ++p) {
                const int r = p * 8 + lrow;
                float4 vv = *(const float4*)(x + (row0 + r) * WW + wbase + lcol);
                *(float4*)&xs[r][lcol] = vv;
            }
            __syncthreads();

            if (dir == 0) {
                for (int j = 0; j < 32; ++j) {
                    const float v = xs[t][j];
                    const int wg = wbase + j;
                    const float o = (wg == 0) ? v : relu_f(carry * w + v);
                    carry = o;
                    xs[t][j] = o;          // in-place: thread owns row t
                }
            } else {
                for (int j = 31; j >= 0; --j) {
                    const float v = xs[t][j];
                    const int wg = wbase + j;
                    const float o = (wg == WW - 1) ? v : relu_f(carry * w + v);
                    carry = o;
                    xs[t][j] = o;
                }
            }
            __syncthreads();

            for (int p = 0; p < 8; ++p) {
                const int r = p * 8 + lrow;
                float4 vv = *(const float4*)&xs[r][lcol];
                *(float4*)(op + (row0 + r) * WW + wbase + lcol) = vv;
            }
            __syncthreads();
        }
    }
}

extern "C" void kernel_launch(void* const* d_in, const int* in_sizes, int n_in,
                              void* d_out, int out_size, void* d_ws, size_t ws_size,
                              hipStream_t stream) {
    const float* x      = (const float*)d_in[0];
    const float* w_up   = (const float*)d_in[1];
    const float* w_down = (const float*)d_in[2];
    const float* w_left = (const float*)d_in[3];
    const float* w_right= (const float*)d_in[4];
    float* out = (float*)d_out;

    hipLaunchKernelGGL(irnn_all, dim3(2560), dim3(64), 0, stream,
                       x, out, w_up, w_down, w_left, w_right);
}

// Round 3
// 194.015 us; speedup vs baseline: 1.0419x; 1.0419x over previous
//
#include <hip/hip_runtime.h>

// IRNN 8-direction scan. x: [8,32,256,256] f32. Outputs (concat order):
// 0 up, 1 right, 2 down, 3 left, 4 zuoxia, 5 youxia, 6 zuoshang(==zuoxia), 7 youshang.
//
// One kernel, 3840 one-wave blocks:
//   [0,512)     down  -> out2   (half-width per block, float2/lane)
//   [512,1024)  up    -> out0   (half-width)
//   [1024,1280) zuoxia-> out4+out6 (full width, float4/lane)
//   [1280,1536) youxia-> out5
//   [1536,1792) youshang-> out7
//   [1792,2816) right -> out1   (64 rows/block, LDS chunked scan, reg-pipelined)
//   [2816,3840) left  -> out3

namespace {
constexpr int HH = 256;
constexpr int WW = 256;
constexpr int PLANE = HH * WW;
constexpr size_t TEN = (size_t)PLANE * 256;

__device__ __forceinline__ float relu_f(float a) { return fmaxf(a, 0.0f); }
} // namespace

__global__ __launch_bounds__(64) void irnn_all(
    const float* __restrict__ x, float* __restrict__ out,
    const float* __restrict__ wup_p, const float* __restrict__ wdn_p,
    const float* __restrict__ wlf_p, const float* __restrict__ wrt_p)
{
    __shared__ float xs[64][33];    // horizontal roles only

    const int bid = blockIdx.x;
    const int t = threadIdx.x;

    if (bid < 512) {
        // ---------- down: out2, half-width ----------
        const int plane = bid >> 1, hf = bid & 1;
        const float wd = *wdn_p;
        const float* xp = x + (size_t)plane * PLANE + hf * 128 + t * 2;
        float* op = out + 2 * TEN + (size_t)plane * PLANE + hf * 128 + t * 2;

        float2 c = *(const float2*)xp;
        *(float2*)op = c;
        float2 buf[8];
        #pragma unroll
        for (int k = 0; k < 8; ++k) buf[k] = *(const float2*)(xp + (1 + k) * WW);
        #pragma unroll 8
        for (int h = 1; h < 256; ++h) {
            float2 v = buf[(h - 1) & 7];
            if (h + 8 < 256) buf[(h - 1) & 7] = *(const float2*)(xp + (h + 8) * WW);
            c.x = relu_f(c.x * wd + v.x);
            c.y = relu_f(c.y * wd + v.y);
            *(float2*)(op + h * WW) = c;
        }
    } else if (bid < 1024) {
        // ---------- up: out0, half-width ----------
        const int b = bid - 512;
        const int plane = b >> 1, hf = b & 1;
        const float wu = *wup_p;
        const float* xp = x + (size_t)plane * PLANE + hf * 128 + t * 2;
        float* op = out + 0 * TEN + (size_t)plane * PLANE + hf * 128 + t * 2;

        float2 c = *(const float2*)(xp + 255 * WW);
        *(float2*)(op + 255 * WW) = c;
        float2 buf[8];
        #pragma unroll
        for (int k = 0; k < 8; ++k) buf[k] = *(const float2*)(xp + (254 - k) * WW);
        #pragma unroll 8
        for (int i = 0; i < 255; ++i) {
            const int h = 254 - i;
            float2 v = buf[i & 7];
            if (i + 8 < 255) buf[i & 7] = *(const float2*)(xp + (254 - (i + 8)) * WW);
            c.x = relu_f(c.x * wu + v.x);
            c.y = relu_f(c.y * wu + v.y);
            *(float2*)(op + h * WW) = c;
        }
    } else if (bid < 1280) {
        // ---------- zuoxia: out4 + out6 ----------
        const int plane = bid - 1024;
        const float wd = *wdn_p;
        const float* xp = x + (size_t)plane * PLANE + t * 4;
        float* o4 = out + 4 * TEN + (size_t)plane * PLANE + t * 4;
        float* o6 = out + 6 * TEN + (size_t)plane * PLANE + t * 4;

        float4 c = *(const float4*)xp;
        *(float4*)o4 = c; *(float4*)o6 = c;
        float4 buf[8];
        #pragma unroll
        for (int k = 0; k < 8; ++k) buf[k] = *(const float4*)(xp + (1 + k) * WW);
        #pragma unroll 8
        for (int h = 1; h < 256; ++h) {
            float4 v = buf[(h - 1) & 7];
            if (h + 8 < 256) buf[(h - 1) & 7] = *(const float4*)(xp + (h + 8) * WW);
            float pw = __shfl_up(c.w, 1);
            float4 n;
            n.x = (t == 0) ? v.x : relu_f(pw * wd + v.x);
            n.y = relu_f(c.x * wd + v.y);
            n.z = relu_f(c.y * wd + v.z);
            n.w = relu_f(c.z * wd + v.w);
            *(float4*)(o4 + h * WW) = n;
            *(float4*)(o6 + h * WW) = n;
            c = n;
        }
    } else if (bid < 1536) {
        // ---------- youxia: out5 ----------
        const int plane = bid - 1280;
        const float wd = *wdn_p;
        const float* xp = x + (size_t)plane * PLANE + t * 4;
        float* o5 = out + 5 * TEN + (size_t)plane * PLANE + t * 4;

        float4 c = *(const float4*)xp;
        *(float4*)o5 = c;
        float4 buf[8];
        #pragma unroll
        for (int k = 0; k < 8; ++k) buf[k] = *(const float4*)(xp + (1 + k) * WW);
        #pragma unroll 8
        for (int h = 1; h < 256; ++h) {
            float4 v = buf[(h - 1) & 7];
            if (h + 8 < 256) buf[(h - 1) & 7] = *(const float4*)(xp + (h + 8) * WW);
            float nx = __shfl_down(c.x, 1);
            float4 n;
            n.x = relu_f(c.y * wd + v.x);
            n.y = relu_f(c.z * wd + v.y);
            n.z = relu_f(c.w * wd + v.z);
            n.w = (t == 63) ? v.w : relu_f(nx * wd + v.w);
            *(float4*)(o5 + h * WW) = n;
            c = n;
        }
    } else if (bid < 1792) {
        // ---------- youshang: out7 ----------
        const int plane = bid - 1536;
        const float wd = *wdn_p;
        const float* xp = x + (size_t)plane * PLANE + t * 4;
        float* o7 = out + 7 * TEN + (size_t)plane * PLANE + t * 4;

        float4 c = *(const float4*)(xp + 255 * WW);
        *(float4*)(o7 + 255 * WW) = c;
        float4 buf[8];
        #pragma unroll
        for (int k = 0; k < 8; ++k) buf[k] = *(const float4*)(xp + (254 - k) * WW);
        #pragma unroll 8
        for (int i = 0; i < 255; ++i) {
            const int h = 254 - i;
            float4 v = buf[i & 7];
            if (i + 8 < 255) buf[i & 7] = *(const float4*)(xp + (254 - (i + 8)) * WW);
            float pw = __shfl_up(c.w, 1);
            float4 n;
            n.x = (t == 0) ? v.x : relu_f(pw * wd + v.x);
            n.y = relu_f(c.x * wd + v.y);
            n.z = relu_f(c.y * wd + v.z);
            n.w = relu_f(c.z * wd + v.w);
            *(float4*)(o7 + h * WW) = n;
            c = n;
        }
    } else {
        // ---------- horizontal: right (out1) / left (out3) ----------
        const int hb = bid - 1792;
        const int dir = hb >> 10;
        const int rb = hb & 1023;
        const size_t row0 = (size_t)rb * 64;
        const int lrow = t >> 3;
        const int lcol = (t & 7) * 4;

        const float w = dir ? *wlf_p : *wrt_p;
        float* op = out + (size_t)(dir ? 3 : 1) * TEN;

        float carry = 0.0f;
        float4 Ra[8], Rb[8];

        // preload chunk 0 (in scan order)
        {
            const int wb0 = (dir ? 7 : 0) * 32;
            #pragma unroll
            for (int p = 0; p < 8; ++p)
                Ra[p] = *(const float4*)(x + (row0 + p * 8 + lrow) * WW + wb0 + lcol);
        }

        auto body = [&](float4 (&cur)[8], float4 (&nxt)[8], int ci) {
            const int cw = dir ? (7 - ci) : ci;
            const int wbase = cw * 32;

            __syncthreads();   // previous chunk fully stored from LDS
            #pragma unroll
            for (int p = 0; p < 8; ++p)
                *(float4*)&xs[p * 8 + lrow][lcol] = cur[p];

            if (ci + 1 < 8) {  // issue next-chunk global loads (latency hidden)
                const int wb2 = (dir ? (7 - (ci + 1)) : (ci + 1)) * 32;
                #pragma unroll
                for (int p = 0; p < 8; ++p)
                    nxt[p] = *(const float4*)(x + (row0 + p * 8 + lrow) * WW + wb2 + lcol);
            }
            __syncthreads();

            if (dir == 0) {
                #pragma unroll
                for (int j = 0; j < 32; ++j) {
                    const float v = xs[t][j];
                    const int wg = wbase + j;
                    const float o = (wg == 0) ? v : relu_f(carry * w + v);
                    carry = o;
                    xs[t][j] = o;
                }
            } else {
                #pragma unroll
                for (int j = 31; j >= 0; --j) {
                    const float v = xs[t][j];
                    const int wg = wbase + j;
                    const float o = (wg == WW - 1) ? v : relu_f(carry * w + v);
                    carry = o;
                    xs[t][j] = o;
                }
            }
            __syncthreads();

            #pragma unroll
            for (int p = 0; p < 8; ++p)
                *(float4*)(op + (row0 + p * 8 + lrow) * WW + wbase + lcol) =
                    *(const float4*)&xs[p * 8 + lrow][lcol];
        };

        for (int cp = 0; cp < 4; ++cp) {
            body(Ra, Rb, 2 * cp);
            body(Rb, Ra, 2 * cp + 1);
        }
    }
}

extern "C" void kernel_launch(void* const* d_in, const int* in_sizes, int n_in,
                              void* d_out, int out_size, void* d_ws, size_t ws_size,
                              hipStream_t stream) {
    const float* x      = (const float*)d_in[0];
    const float* w_up   = (const float*)d_in[1];
    const float* w_down = (const float*)d_in[2];
    const float* w_left = (const float*)d_in[3];
    const float* w_right= (const float*)d_in[4];
    float* out = (float*)d_out;

    hipLaunchKernelGGL(irnn_all, dim3(3840), dim3(64), 0, stream,
                       x, out, w_up, w_down, w_left, w_right);
}

// Round 4
// 188.941 us; speedup vs baseline: 1.0698x; 1.0269x over previous
//
#include <hip/hip_runtime.h>

// IRNN 8-direction scan. x: [8,32,256,256] f32. Outputs (concat order):
// 0 up, 1 right, 2 down, 3 left, 4 zuoxia, 5 youxia, 6 zuoshang(==zuoxia), 7 youshang.
//
// Two kernels (two-kernel structure measured faster than merged in R1 vs R2/R3):
//  irnn_v (1792 one-wave blocks):
//   [0,512)     down  -> out2  (half-width strips, float2/lane)
//   [512,1024)  up    -> out0  (half-width strips)
//   [1024,1280) zuoxia-> out4+out6 (full width, float4/lane, shfl shift)
//   [1280,1536) youxia-> out5
//   [1536,1792) youshang-> out7
//  irnn_h (2048 one-wave blocks): right -> out1, left -> out3, 64 rows/block.

namespace {
constexpr int HH = 256;
constexpr int WW = 256;
constexpr int PLANE = HH * WW;
constexpr size_t TEN = (size_t)PLANE * 256;

__device__ __forceinline__ float relu_f(float a) { return fmaxf(a, 0.0f); }
} // namespace

__global__ __launch_bounds__(64) void irnn_v(
    const float* __restrict__ x, float* __restrict__ out,
    const float* __restrict__ wup_p, const float* __restrict__ wdn_p)
{
    const int bid = blockIdx.x;
    const int t = threadIdx.x;

    if (bid < 512) {
        // ---------- down -> out2 (float2, half-width strip) ----------
        const int plane = bid >> 1, hf = bid & 1;
        const float wd = *wdn_p;
        const float* xp = x + (size_t)plane * PLANE + hf * 128 + t * 2;
        float* op = out + 2 * TEN + (size_t)plane * PLANE + hf * 128 + t * 2;

        float2 c = *(const float2*)xp;
        *(float2*)op = c;
        float2 buf[8];
        #pragma unroll
        for (int k = 0; k < 8; ++k) buf[k] = *(const float2*)(xp + (1 + k) * WW);
        #pragma unroll 1
        for (int g = 0; g < 31; ++g) {
            #pragma unroll
            for (int k = 0; k < 8; ++k) {
                const int r = 1 + 8 * g + k;
                float2 v = buf[k];
                const int pr = (r + 8 < 256) ? (r + 8) : 255;   // clamped prefetch
                buf[k] = *(const float2*)(xp + pr * WW);
                c.x = relu_f(c.x * wd + v.x);
                c.y = relu_f(c.y * wd + v.y);
                *(float2*)(op + r * WW) = c;
            }
        }
        #pragma unroll
        for (int k = 0; k < 7; ++k) {              // rows 249..255, all static
            const int r = 249 + k;
            float2 v = buf[k];
            c.x = relu_f(c.x * wd + v.x);
            c.y = relu_f(c.y * wd + v.y);
            *(float2*)(op + r * WW) = c;
        }
    } else if (bid < 1024) {
        // ---------- up -> out0 (float2, half-width strip) ----------
        const int b = bid - 512;
        const int plane = b >> 1, hf = b & 1;
        const float wu = *wup_p;
        const float* xp = x + (size_t)plane * PLANE + hf * 128 + t * 2;
        float* op = out + 0 * TEN + (size_t)plane * PLANE + hf * 128 + t * 2;

        float2 c = *(const float2*)(xp + 255 * WW);
        *(float2*)(op + 255 * WW) = c;
        float2 buf[8];
        #pragma unroll
        for (int k = 0; k < 8; ++k) buf[k] = *(const float2*)(xp + (254 - k) * WW);
        #pragma unroll 1
        for (int g = 0; g < 31; ++g) {
            #pragma unroll
            for (int k = 0; k < 8; ++k) {
                const int h = 254 - (8 * g + k);
                float2 v = buf[k];
                const int ph = (h - 8 >= 0) ? (h - 8) : 0;
                buf[k] = *(const float2*)(xp + ph * WW);
                c.x = relu_f(c.x * wu + v.x);
                c.y = relu_f(c.y * wu + v.y);
                *(float2*)(op + h * WW) = c;
            }
        }
        #pragma unroll
        for (int k = 0; k < 7; ++k) {              // rows 6..0
            const int h = 6 - k;
            float2 v = buf[k];
            c.x = relu_f(c.x * wu + v.x);
            c.y = relu_f(c.y * wu + v.y);
            *(float2*)(op + h * WW) = c;
        }
    } else if (bid < 1280) {
        // ---------- zuoxia -> out4 + out6 (float4, full width) ----------
        const int plane = bid - 1024;
        const float wd = *wdn_p;
        const float* xp = x + (size_t)plane * PLANE + t * 4;
        float* o4 = out + 4 * TEN + (size_t)plane * PLANE + t * 4;
        float* o6 = out + 6 * TEN + (size_t)plane * PLANE + t * 4;

        float4 c = *(const float4*)xp;
        *(float4*)o4 = c; *(float4*)o6 = c;
        float4 buf[8];
        #pragma unroll
        for (int k = 0; k < 8; ++k) buf[k] = *(const float4*)(xp + (1 + k) * WW);
        #pragma unroll 1
        for (int g = 0; g < 31; ++g) {
            #pragma unroll
            for (int k = 0; k < 8; ++k) {
                const int r = 1 + 8 * g + k;
                float4 v = buf[k];
                const int pr = (r + 8 < 256) ? (r + 8) : 255;
                buf[k] = *(const float4*)(xp + pr * WW);
                float pw = __shfl_up(c.w, 1);
                float4 n;
                n.x = (t == 0) ? v.x : relu_f(pw * wd + v.x);
                n.y = relu_f(c.x * wd + v.y);
                n.z = relu_f(c.y * wd + v.z);
                n.w = relu_f(c.z * wd + v.w);
                *(float4*)(o4 + r * WW) = n;
                *(float4*)(o6 + r * WW) = n;
                c = n;
            }
        }
        #pragma unroll
        for (int k = 0; k < 7; ++k) {
            const int r = 249 + k;
            float4 v = buf[k];
            float pw = __shfl_up(c.w, 1);
            float4 n;
            n.x = (t == 0) ? v.x : relu_f(pw * wd + v.x);
            n.y = relu_f(c.x * wd + v.y);
            n.z = relu_f(c.y * wd + v.z);
            n.w = relu_f(c.z * wd + v.w);
            *(float4*)(o4 + r * WW) = n;
            *(float4*)(o6 + r * WW) = n;
            c = n;
        }
    } else if (bid < 1536) {
        // ---------- youxia -> out5 ----------
        const int plane = bid - 1280;
        const float wd = *wdn_p;
        const float* xp = x + (size_t)plane * PLANE + t * 4;
        float* o5 = out + 5 * TEN + (size_t)plane * PLANE + t * 4;

        float4 c = *(const float4*)xp;
        *(float4*)o5 = c;
        float4 buf[8];
        #pragma unroll
        for (int k = 0; k < 8; ++k) buf[k] = *(const float4*)(xp + (1 + k) * WW);
        #pragma unroll 1
        for (int g = 0; g < 31; ++g) {
            #pragma unroll
            for (int k = 0; k < 8; ++k) {
                const int r = 1 + 8 * g + k;
                float4 v = buf[k];
                const int pr = (r + 8 < 256) ? (r + 8) : 255;
                buf[k] = *(const float4*)(xp + pr * WW);
                float nx = __shfl_down(c.x, 1);
                float4 n;
                n.x = relu_f(c.y * wd + v.x);
                n.y = relu_f(c.z * wd + v.y);
                n.z = relu_f(c.w * wd + v.z);
                n.w = (t == 63) ? v.w : relu_f(nx * wd + v.w);
                *(float4*)(o5 + r * WW) = n;
                c = n;
            }
        }
        #pragma unroll
        for (int k = 0; k < 7; ++k) {
            const int r = 249 + k;
            float4 v = buf[k];
            float nx = __shfl_down(c.x, 1);
            float4 n;
            n.x = relu_f(c.y * wd + v.x);
            n.y = relu_f(c.z * wd + v.y);
            n.z = relu_f(c.w * wd + v.z);
            n.w = (t == 63) ? v.w : relu_f(nx * wd + v.w);
            *(float4*)(o5 + r * WW) = n;
            c = n;
        }
    } else {
        // ---------- youshang -> out7 (backward h) ----------
        const int plane = bid - 1536;
        const float wd = *wdn_p;
        const float* xp = x + (size_t)plane * PLANE + t * 4;
        float* o7 = out + 7 * TEN + (size_t)plane * PLANE + t * 4;

        float4 c = *(const float4*)(xp + 255 * WW);
        *(float4*)(o7 + 255 * WW) = c;
        float4 buf[8];
        #pragma unroll
        for (int k = 0; k < 8; ++k) buf[k] = *(const float4*)(xp + (254 - k) * WW);
        #pragma unroll 1
        for (int g = 0; g < 31; ++g) {
            #pragma unroll
            for (int k = 0; k < 8; ++k) {
                const int h = 254 - (8 * g + k);
                float4 v = buf[k];
                const int ph = (h - 8 >= 0) ? (h - 8) : 0;
                buf[k] = *(const float4*)(xp + ph * WW);
                float pw = __shfl_up(c.w, 1);
                float4 n;
                n.x = (t == 0) ? v.x : relu_f(pw * wd + v.x);
                n.y = relu_f(c.x * wd + v.y);
                n.z = relu_f(c.y * wd + v.z);
                n.w = relu_f(c.z * wd + v.w);
                *(float4*)(o7 + h * WW) = n;
                c = n;
            }
        }
        #pragma unroll
        for (int k = 0; k < 7; ++k) {
            const int h = 6 - k;
            float4 v = buf[k];
            float pw = __shfl_up(c.w, 1);
            float4 n;
            n.x = (t == 0) ? v.x : relu_f(pw * wd + v.x);
            n.y = relu_f(c.x * wd + v.y);
            n.z = relu_f(c.y * wd + v.z);
            n.w = relu_f(c.z * wd + v.w);
            *(float4*)(o7 + h * WW) = n;
            c = n;
        }
    }
}

__global__ __launch_bounds__(64) void irnn_h(
    const float* __restrict__ x, float* __restrict__ out,
    const float* __restrict__ wlf_p, const float* __restrict__ wrt_p)
{
    __shared__ float xs[64][33];      // single in-place buffer; stride 33 (conflict-free)

    const int bid = blockIdx.x;
    const int t = threadIdx.x;
    const int dir = bid >> 10;        // 0: right, 1: left
    const int rb = bid & 1023;
    const size_t row0 = (size_t)rb * 64;
    const int lrow = t >> 3;
    const int lcol = (t & 7) * 4;

    const float w = dir ? *wlf_p : *wrt_p;
    float* op = out + (size_t)(dir ? 3 : 1) * TEN;

    float carry = 0.0f;
    float4 Ra[8], Rb[8];

    {   // preload first chunk (in scan order)
        const int wb0 = (dir ? 7 : 0) * 32;
        #pragma unroll
        for (int p = 0; p < 8; ++p)
            Ra[p] = *(const float4*)(x + (row0 + p * 8 + lrow) * WW + wb0 + lcol);
    }

    auto body = [&](float4 (&cur)[8], float4 (&nxt)[8], int ci) {
        const int cw = dir ? (7 - ci) : ci;
        const int wbase = cw * 32;

        // transpose-in: regs -> LDS (coalesced layout)
        #pragma unroll
        for (int p = 0; p < 8; ++p)
            *(float4*)&xs[p * 8 + lrow][lcol] = cur[p];

        // issue next-chunk global loads early (latency hides under scan)
        if (ci + 1 < 8) {
            const int wb2 = (dir ? (7 - (ci + 1)) : (ci + 1)) * 32;
            #pragma unroll
            for (int p = 0; p < 8; ++p)
                nxt[p] = *(const float4*)(x + (row0 + p * 8 + lrow) * WW + wb2 + lcol);
        }
        __syncthreads();

        // read my row into registers (scalar b32: stride-33 is conflict-free)
        float q[32];
        #pragma unroll
        for (int j = 0; j < 32; ++j) q[j] = xs[t][j];

        // serial scan fully in registers
        if (dir == 0) {
            if (ci == 0) carry = q[0];
            else { q[0] = relu_f(carry * w + q[0]); carry = q[0]; }
            #pragma unroll
            for (int j = 1; j < 32; ++j) { q[j] = relu_f(carry * w + q[j]); carry = q[j]; }
        } else {
            if (ci == 0) carry = q[31];
            else { q[31] = relu_f(carry * w + q[31]); carry = q[31]; }
            #pragma unroll
            for (int j = 30; j >= 0; --j) { q[j] = relu_f(carry * w + q[j]); carry = q[j]; }
        }

        // write my row back
        #pragma unroll
        for (int j = 0; j < 32; ++j) xs[t][j] = q[j];
        __syncthreads();

        // coalesced store LDS -> global
        #pragma unroll
        for (int p = 0; p < 8; ++p)
            *(float4*)(op + (row0 + p * 8 + lrow) * WW + wbase + lcol) =
                *(const float4*)&xs[p * 8 + lrow][lcol];
        __syncthreads();   // buffer reuse guard
    };

    #pragma unroll 1
    for (int cp = 0; cp < 4; ++cp) {
        body(Ra, Rb, 2 * cp);
        body(Rb, Ra, 2 * cp + 1);
    }
}

extern "C" void kernel_launch(void* const* d_in, const int* in_sizes, int n_in,
                              void* d_out, int out_size, void* d_ws, size_t ws_size,
                              hipStream_t stream) {
    const float* x      = (const float*)d_in[0];
    const float* w_up   = (const float*)d_in[1];
    const float* w_down = (const float*)d_in[2];
    const float* w_left = (const float*)d_in[3];
    const float* w_right= (const float*)d_in[4];
    float* out = (float*)d_out;

    hipLaunchKernelGGL(irnn_v, dim3(1792), dim3(64), 0, stream,
                       x, out, w_up, w_down);
    hipLaunchKernelGGL(irnn_h, dim3(2048), dim3(64), 0, stream,
                       x, out, w_left, w_right);
}

// Round 5
// 154.951 us; speedup vs baseline: 1.3045x; 1.2194x over previous
//
#include <hip/hip_runtime.h>

// IRNN 8-direction scan. x: [8,32,256,256] f32. Outputs (concat order):
// 0 up, 1 right, 2 down, 3 left, 4 zuoxia, 5 youxia, 6 zuoshang(==zuoxia), 7 youshang.
//
// Round-5: R1's exact per-block code, merged into ONE kernel (isolating the
// merge variable). 3328 one-wave blocks:
//   [0,1280)    vertical, role = bid>>8: 0 down(out2) 1 up(out0)
//               2 zuoxia(out4+out6) 3 youxia(out5) 4 youshang(out7)
//   [1280,2304) horizontal right -> out1 (64 rows/block, in-place LDS scan)
//   [2304,3328) horizontal left  -> out3

namespace {
constexpr int HH = 256;
constexpr int WW = 256;
constexpr int PLANE = HH * WW;
constexpr size_t TEN = (size_t)PLANE * 256;

__device__ __forceinline__ float relu_f(float a) { return fmaxf(a, 0.0f); }
} // namespace

__global__ __launch_bounds__(64) void irnn_all(
    const float* __restrict__ x, float* __restrict__ out,
    const float* __restrict__ wup_p, const float* __restrict__ wdn_p,
    const float* __restrict__ wlf_p, const float* __restrict__ wrt_p)
{
    __shared__ float xs[64][33];   // horizontal only; 8.4 KiB -> 19 blocks/CU LDS cap

    const int bid = blockIdx.x;
    const int t = threadIdx.x;

    if (bid < 1280) {
        const int role = bid >> 8;
        const int plane = bid & 255;
        const float* xp = x + (size_t)plane * PLANE + t * 4;

        if (role == 0) {                 // down -> out2
            const float wd = *wdn_p;
            float* op = out + 2 * TEN + (size_t)plane * PLANE + t * 4;
            float4 c = *(const float4*)xp;
            *(float4*)op = c;
            for (int h = 1; h < HH; ++h) {
                float4 v = *(const float4*)(xp + h * WW);
                c.x = relu_f(c.x * wd + v.x);
                c.y = relu_f(c.y * wd + v.y);
                c.z = relu_f(c.z * wd + v.z);
                c.w = relu_f(c.w * wd + v.w);
                *(float4*)(op + h * WW) = c;
            }
        } else if (role == 1) {          // up -> out0
            const float wu = *wup_p;
            float* op = out + 0 * TEN + (size_t)plane * PLANE + t * 4;
            float4 c = *(const float4*)(xp + (HH - 1) * WW);
            *(float4*)(op + (HH - 1) * WW) = c;
            for (int h = HH - 2; h >= 0; --h) {
                float4 v = *(const float4*)(xp + h * WW);
                c.x = relu_f(c.x * wu + v.x);
                c.y = relu_f(c.y * wu + v.y);
                c.z = relu_f(c.z * wu + v.z);
                c.w = relu_f(c.w * wu + v.w);
                *(float4*)(op + h * WW) = c;
            }
        } else if (role == 2) {          // zuoxia -> out4 + out6
            const float wd = *wdn_p;
            float* o4 = out + 4 * TEN + (size_t)plane * PLANE + t * 4;
            float* o6 = out + 6 * TEN + (size_t)plane * PLANE + t * 4;
            float4 c = *(const float4*)xp;
            *(float4*)o4 = c;
            *(float4*)o6 = c;
            for (int h = 1; h < HH; ++h) {
                float4 v = *(const float4*)(xp + h * WW);
                float pw = __shfl_up(c.w, 1);
                float4 n;
                n.x = (t == 0) ? v.x : relu_f(pw * wd + v.x);
                n.y = relu_f(c.x * wd + v.y);
                n.z = relu_f(c.y * wd + v.z);
                n.w = relu_f(c.z * wd + v.w);
                *(float4*)(o4 + h * WW) = n;
                *(float4*)(o6 + h * WW) = n;
                c = n;
            }
        } else if (role == 3) {          // youxia -> out5
            const float wd = *wdn_p;
            float* o5 = out + 5 * TEN + (size_t)plane * PLANE + t * 4;
            float4 c = *(const float4*)xp;
            *(float4*)o5 = c;
            for (int h = 1; h < HH; ++h) {
                float4 v = *(const float4*)(xp + h * WW);
                float nx = __shfl_down(c.x, 1);
                float4 n;
                n.x = relu_f(c.y * wd + v.x);
                n.y = relu_f(c.z * wd + v.y);
                n.z = relu_f(c.w * wd + v.z);
                n.w = (t == 63) ? v.w : relu_f(nx * wd + v.w);
                *(float4*)(o5 + h * WW) = n;
                c = n;
            }
        } else {                         // youshang -> out7
            const float wd = *wdn_p;
            float* o7 = out + 7 * TEN + (size_t)plane * PLANE + t * 4;
            float4 c = *(const float4*)(xp + (HH - 1) * WW);
            *(float4*)(o7 + (HH - 1) * WW) = c;
            for (int h = HH - 2; h >= 0; --h) {
                float4 v = *(const float4*)(xp + h * WW);
                float pw = __shfl_up(c.w, 1);
                float4 n;
                n.x = (t == 0) ? v.x : relu_f(pw * wd + v.x);
                n.y = relu_f(c.x * wd + v.y);
                n.z = relu_f(c.y * wd + v.z);
                n.w = relu_f(c.z * wd + v.w);
                *(float4*)(o7 + h * WW) = n;
                c = n;
            }
        }
    } else {
        // ---- horizontal: right (out1) / left (out3), 64 rows/block ----
        const int hb = bid - 1280;
        const int dir = hb >> 10;
        const int rb = hb & 1023;
        const size_t row0 = (size_t)rb * 64;
        const int lrow = t >> 3;          // 8 lanes per row for load/store
        const int lcol = (t & 7) * 4;

        const float w = dir ? *wlf_p : *wrt_p;
        float* op = out + (size_t)(dir ? 3 : 1) * TEN;

        float carry = 0.0f;
        for (int ci = 0; ci < 8; ++ci) {
            const int cw = dir ? (7 - ci) : ci;
            const int wbase = cw * 32;

            for (int p = 0; p < 8; ++p) {
                const int r = p * 8 + lrow;
                float4 v = *(const float4*)(x + (row0 + r) * WW + wbase + lcol);
                *(float4*)&xs[r][lcol] = v;
            }
            __syncthreads();

            if (dir == 0) {
                for (int j = 0; j < 32; ++j) {
                    const float v = xs[t][j];
                    const int wg = wbase + j;
                    const float o = (wg == 0) ? v : relu_f(carry * w + v);
                    carry = o;
                    xs[t][j] = o;          // in-place: thread owns row t
                }
            } else {
                for (int j = 31; j >= 0; --j) {
                    const float v = xs[t][j];
                    const int wg = wbase + j;
                    const float o = (wg == WW - 1) ? v : relu_f(carry * w + v);
                    carry = o;
                    xs[t][j] = o;
                }
            }
            __syncthreads();

            for (int p = 0; p < 8; ++p) {
                const int r = p * 8 + lrow;
                float4 v = *(const float4*)&xs[r][lcol];
                *(float4*)(op + (row0 + r) * WW + wbase + lcol) = v;
            }
            __syncthreads();
        }
    }
}

extern "C" void kernel_launch(void* const* d_in, const int* in_sizes, int n_in,
                              void* d_out, int out_size, void* d_ws, size_t ws_size,
                              hipStream_t stream) {
    const float* x      = (const float*)d_in[0];
    const float* w_up   = (const float*)d_in[1];
    const float* w_down = (const float*)d_in[2];
    const float* w_left = (const float*)d_in[3];
    const float* w_right= (const float*)d_in[4];
    float* out = (float*)d_out;

    hipLaunchKernelGGL(irnn_all, dim3(3328), dim3(64), 0, stream,
                       x, out, w_up, w_down, w_left, w_right);
}

// Round 6
// 124.847 us; speedup vs baseline: 1.6191x; 1.2411x over previous
//
#include <hip/hip_runtime.h>

// IRNN 8-direction scan. x: [8,32,256,256] f32. Outputs (concat order):
// 0 up, 1 right, 2 down, 3 left, 4 zuoxia, 5 youxia, 6 zuoshang(==zuoxia), 7 youshang.
//
// Round-6: R1 structure verbatim (two kernels, best measured: 148us), with ONE
// change: all output stores are non-temporal (nt) so the 537MB write stream
// does not thrash L3, keeping x resident across the 7 read passes.
// Theory: R1 was HBM-bound at ~1GB (writes + uncached re-reads); nt writes
// cut HBM traffic to ~620MB.

namespace {
constexpr int HH = 256;
constexpr int WW = 256;
constexpr int PLANE = HH * WW;                       // 65536
constexpr size_t TEN = (size_t)PLANE * 256;          // elems per output tensor

__device__ __forceinline__ float relu_f(float a) { return fmaxf(a, 0.0f); }

typedef float v4f __attribute__((ext_vector_type(4)));

__device__ __forceinline__ void nt_store4(float* p, const float4& v) {
    v4f t; t.x = v.x; t.y = v.y; t.z = v.z; t.w = v.w;
    __builtin_nontemporal_store(t, (v4f*)p);
}
} // namespace

// ---------- vertical family: one wave (64 threads) per (role, plane) ----------
// role 0: down -> out2 ; 1: up -> out0 ; 2: zuoxia -> out4+out6 ;
// role 3: youxia -> out5 ; 4: youshang -> out7
__global__ __launch_bounds__(64) void irnn_vertical(
    const float* __restrict__ x, float* __restrict__ out,
    const float* __restrict__ wup_p, const float* __restrict__ wdn_p)
{
    const int bid = blockIdx.x;
    const int role = bid >> 8;       // 5 roles x 256 planes
    const int plane = bid & 255;
    const int t = threadIdx.x;       // lane owns columns 4t..4t+3

    const float* xp = x + (size_t)plane * PLANE + t * 4;

    if (role == 0) {                 // top_down: out[h]=relu(out[h-1]*wd+x[h])
        const float wd = *wdn_p;
        float* op = out + 2 * TEN + (size_t)plane * PLANE + t * 4;
        float4 c = *(const float4*)xp;
        nt_store4(op, c);
        for (int h = 1; h < HH; ++h) {
            float4 v = *(const float4*)(xp + h * WW);
            c.x = relu_f(c.x * wd + v.x);
            c.y = relu_f(c.y * wd + v.y);
            c.z = relu_f(c.z * wd + v.z);
            c.w = relu_f(c.w * wd + v.w);
            nt_store4(op + h * WW, c);
        }
    } else if (role == 1) {          // top_up: out[h]=relu(out[h+1]*wu+x[h])
        const float wu = *wup_p;
        float* op = out + 0 * TEN + (size_t)plane * PLANE + t * 4;
        float4 c = *(const float4*)(xp + (HH - 1) * WW);
        nt_store4(op + (HH - 1) * WW, c);
        for (int h = HH - 2; h >= 0; --h) {
            float4 v = *(const float4*)(xp + h * WW);
            c.x = relu_f(c.x * wu + v.x);
            c.y = relu_f(c.y * wu + v.y);
            c.z = relu_f(c.z * wu + v.z);
            c.w = relu_f(c.w * wu + v.w);
            nt_store4(op + h * WW, c);
        }
    } else if (role == 2) {          // zuoxia/zuoshang: out[h][w]=relu(out[h-1][w-1]*wd+x[h][w])
        const float wd = *wdn_p;
        float* o4 = out + 4 * TEN + (size_t)plane * PLANE + t * 4;
        float* o6 = out + 6 * TEN + (size_t)plane * PLANE + t * 4;
        float4 c = *(const float4*)xp;   // h=0 row pass-through
        nt_store4(o4, c);
        nt_store4(o6, c);
        for (int h = 1; h < HH; ++h) {
            float4 v = *(const float4*)(xp + h * WW);
            float pw = __shfl_up(c.w, 1);     // lane t-1's element 3 == column 4t-1
            float4 n;
            n.x = (t == 0) ? v.x : relu_f(pw * wd + v.x);   // w==0 pass-through
            n.y = relu_f(c.x * wd + v.y);
            n.z = relu_f(c.y * wd + v.z);
            n.w = relu_f(c.z * wd + v.w);
            nt_store4(o4 + h * WW, n);
            nt_store4(o6 + h * WW, n);
            c = n;
        }
    } else if (role == 3) {          // youxia: out[h][w]=relu(out[h-1][w+1]*wd+x[h][w])
        const float wd = *wdn_p;
        float* o5 = out + 5 * TEN + (size_t)plane * PLANE + t * 4;
        float4 c = *(const float4*)xp;   // h=0 row pass-through
        nt_store4(o5, c);
        for (int h = 1; h < HH; ++h) {
            float4 v = *(const float4*)(xp + h * WW);
            float nx = __shfl_down(c.x, 1);   // lane t+1's element 0 == column 4t+4
            float4 n;
            n.x = relu_f(c.y * wd + v.x);
            n.y = relu_f(c.z * wd + v.y);
            n.z = relu_f(c.w * wd + v.z);
            n.w = (t == 63) ? v.w : relu_f(nx * wd + v.w);  // w==255 pass-through
            nt_store4(o5 + h * WW, n);
            c = n;
        }
    } else {                         // youshang: out[h][w]=relu(out[h+1][w-1]*wd+x[h][w])
        const float wd = *wdn_p;
        float* o7 = out + 7 * TEN + (size_t)plane * PLANE + t * 4;
        float4 c = *(const float4*)(xp + (HH - 1) * WW);   // h=255 pass-through
        nt_store4(o7 + (HH - 1) * WW, c);
        for (int h = HH - 2; h >= 0; --h) {
            float4 v = *(const float4*)(xp + h * WW);
            float pw = __shfl_up(c.w, 1);
            float4 n;
            n.x = (t == 0) ? v.x : relu_f(pw * wd + v.x);   // w==0 pass-through
            n.y = relu_f(c.x * wd + v.y);
            n.z = relu_f(c.y * wd + v.z);
            n.w = relu_f(c.z * wd + v.w);
            nt_store4(o7 + h * WW, n);
            c = n;
        }
    }
}

// ---------- horizontal family: right (out1) and left (out3) ----------
// block = 64 threads = 1 wave; each block owns 64 global rows.
// LDS-staged 64x32 chunks: coalesced global <-> LDS, per-thread scan in LDS.
__global__ __launch_bounds__(64) void irnn_horizontal(
    const float* __restrict__ x, float* __restrict__ out,
    const float* __restrict__ wlf_p, const float* __restrict__ wrt_p)
{
    __shared__ float xs[64][33];
    __shared__ float os[64][33];

    const int bid = blockIdx.x;
    const int dir = bid >> 10;        // 0: right, 1: left
    const int rb  = bid & 1023;       // row-block index (1024 blocks of 64 rows)
    const size_t row0 = (size_t)rb * 64;
    const int t = threadIdx.x;
    const int lrow = t >> 3;          // load/store mapping: 8 lanes per row
    const int lcol = (t & 7) * 4;

    const float w = dir ? *wlf_p : *wrt_p;
    float* op = out + (size_t)(dir ? 3 : 1) * TEN;

    float carry = 0.0f;
    for (int ci = 0; ci < 8; ++ci) {
        const int cw = dir ? (7 - ci) : ci;   // chunk order follows scan direction
        const int wbase = cw * 32;

        // load 64 rows x 32 cols (8 passes, 8 rows/pass, 128B/row segments)
        for (int p = 0; p < 8; ++p) {
            const int r = p * 8 + lrow;
            float4 v = *(const float4*)(x + (row0 + r) * WW + wbase + lcol);
            *(float4*)&xs[r][lcol] = v;
        }
        __syncthreads();

        // per-thread scan of own row t within the chunk
        if (dir == 0) {
            for (int j = 0; j < 32; ++j) {
                const float v = xs[t][j];
                const int wg = wbase + j;
                const float o = (wg == 0) ? v : relu_f(carry * w + v);
                carry = o;
                os[t][j] = o;
            }
        } else {
            for (int j = 31; j >= 0; --j) {
                const float v = xs[t][j];
                const int wg = wbase + j;
                const float o = (wg == WW - 1) ? v : relu_f(carry * w + v);
                carry = o;
                os[t][j] = o;
            }
        }
        __syncthreads();

        // coalesced writeout (non-temporal)
        for (int p = 0; p < 8; ++p) {
            const int r = p * 8 + lrow;
            float4 v = *(const float4*)&os[r][lcol];
            nt_store4(op + (row0 + r) * WW + wbase + lcol, v);
        }
        __syncthreads();
    }
}

extern "C" void kernel_launch(void* const* d_in, const int* in_sizes, int n_in,
                              void* d_out, int out_size, void* d_ws, size_t ws_size,
                              hipStream_t stream) {
    const float* x      = (const float*)d_in[0];
    const float* w_up   = (const float*)d_in[1];
    const float* w_down = (const float*)d_in[2];
    const float* w_left = (const float*)d_in[3];
    const float* w_right= (const float*)d_in[4];
    float* out = (float*)d_out;

    hipLaunchKernelGGL(irnn_vertical, dim3(5 * 256), dim3(64), 0, stream,
                       x, out, w_up, w_down);
    hipLaunchKernelGGL(irnn_horizontal, dim3(2 * 1024), dim3(64), 0, stream,
                       x, out, w_left, w_right);
}